// Round 14
// baseline (318.326 us; speedup 1.0000x reference)
//
#include <hip/hip_runtime.h>
#include <math.h>

// Problem constants (fixed by the reference): x,y are [4, 64, 64, 64] fp32.
constexpr int B_   = 4;
constexpr int C_   = 64;
constexpr int HW   = 4096;         // N = 64*64
constexpr int ROWS = B_ * HW;      // 16384

constexpr float SIGMA    = 0.1f;
constexpr float EPS_MIN  = 1e-5f;
constexpr float EPS_NORM = 1e-12f;
constexpr float LOG2E    = 1.44269504088896340736f;

// Geometry: block = 64 x-rows x HALF the y-range (2048 rows) => grid 512,
// 2 blocks/CU, 8 waves/SIMD -- same per-CU LDS/L2/elem economics as R10's
// XR=64 config (xt=4 kept), double the TLP.  dmin handoff between sweeps
// moves to a kernel boundary + global atomicMin (R1-R5 verified pattern).
constexpr int XR   = 64;           // x-rows per block (4 MFMA col-tiles)
constexpr int YH   = HW / 2;       // 2048 y-rows per block (half range)
constexpr int NW   = 16;           // waves per block
constexpr int YW   = YH / NW;      // 128 y-rows per wave
constexpr int SRW  = 16;           // y-rows per wave-private stage (2 KB)
constexpr int NSW  = YW / SRW;     // 8 stages per sweep
constexpr int GRID = 512;          // (ROWS/XR) * 2

using short8  = __attribute__((ext_vector_type(8))) short;   // 8 bf16
using floatx4 = __attribute__((ext_vector_type(4))) float;

__device__ inline ushort f2bf(float f) {           // RNE float->bf16
    unsigned u = __float_as_uint(f);
    unsigned r = u + 0x7FFFu + ((u >> 16) & 1u);
    return (ushort)(r >> 16);
}

// Async global->LDS, 16B per lane: per-lane global src, wave-uniform LDS
// base (DMA writes base + lane*16).  vmcnt-counted.
__device__ inline void gload16(const ushort* g, void* lds) {
    __builtin_amdgcn_global_load_lds(
        (const __attribute__((address_space(1))) void*)g,
        (__attribute__((address_space(3))) void*)lds, 16, 0, 0);
}

#define WAIT_VMCNT(n) asm volatile("s_waitcnt vmcnt(" #n ")" ::: "memory")

// ---------------------------------------------------------------------------
// Normalize along C; half-point per thread (32 ch) for 2x TLP vs R12.
// xn pre-scaled by -2 (exact in bf16) so MFMA with C-init=2 emits d^2
// directly (verified R9+).  yn rows pre-swizzled: 16B slot s of row n is
// stored at slot s ^ (n&7)  (rule #21: linear DMA + swizzled read).
// Also inits dmin_u (+inf) and total/cnt.
__global__ __launch_bounds__(256) void nrm_kernel(const float* __restrict__ x,
                                                  const float* __restrict__ y,
                                                  ushort* __restrict__ xn,
                                                  ushort* __restrict__ yn,
                                                  unsigned* __restrict__ dmin_u,
                                                  float* __restrict__ total,
                                                  unsigned* __restrict__ cnt) {
    int T = blockIdx.x * 256 + threadIdx.x;        // 0 .. 65535
    if (T == 0) { *total = 0.0f; *cnt = 0u; }
    if (T < ROWS) dmin_u[T] = 0x7F800000u;         // +inf
    int q = T >> 1;                                // point 0..32767
    int h = T & 1;                                 // channel half
    const float* src; ushort* dst; float sgn; bool isy;
    if (q < ROWS) { src = x; dst = xn; sgn = -2.0f; isy = false; }
    else          { src = y; dst = yn; q -= ROWS; sgn = 1.0f; isy = true; }
    int b = q >> 12;
    int n = q & (HW - 1);
    const float* base = src + (size_t)(b * C_) * HW + (size_t)(h * 32) * HW + n;
    float v[32];
    float ss = 0.0f;
#pragma unroll
    for (int j = 0; j < 32; ++j) {
        v[j] = base[(size_t)j * HW];               // coalesced over n (pairs)
        ss = fmaf(v[j], v[j], ss);
    }
    ss += __shfl_xor(ss, 1);                       // combine the two halves
    float scale = sgn / fmaxf(sqrtf(ss), EPS_NORM);
    short8* orow = (short8*)(dst + (size_t)q * C_);
    int sw = isy ? (n & 7) : 0;
#pragma unroll
    for (int j4 = 0; j4 < 4; ++j4) {
        short8 pk;
#pragma unroll
        for (int j = 0; j < 8; ++j) pk[j] = (short)f2bf(v[j4 * 8 + j] * scale);
        orow[(h * 4 + j4) ^ sw] = pk;
    }
}

// ---------------------------------------------------------------------------
// Shared per-block setup for both passes.
#define PASS_SETUP                                                          \
    const int tid  = threadIdx.x;                                           \
    const int wid  = tid >> 6;                     /* 0..15 */              \
    const int lane = tid & 63;                                              \
    const int lrow = lane & 15;                    /* x-col within tile */  \
    const int kgrp = lane >> 4;                    /* k-group 0..3 */       \
    const int pairid = blockIdx.x >> 1;                                     \
    const int half   = blockIdx.x & 1;                                      \
    const int b      = pairid >> 6;                /* 64 pairs per batch */ \
    const int nbase  = (pairid & 63) * XR;                                  \
    const ushort* xb = xn + (size_t)(b * HW + nbase) * C_;                  \
    short8 xf0[4], xf1[4];                                                  \
    _Pragma("unroll")                                                       \
    for (int xt = 0; xt < 4; ++xt) {                                        \
        xf0[xt] = *(const short8*)(xb + (xt * 16 + lrow) * C_ + kgrp * 8);  \
        xf1[xt] = *(const short8*)(xb + (xt * 16 + lrow) * C_ + 32 + kgrp * 8); \
    }                                                                       \
    const ushort* yb = yn + (size_t)(b * HW + half * YH + wid * YW) * C_    \
                          + lane * 8;

// Issue one 2KB stage as 2 x (64 lanes x 16B) DMAs into buffer `buf`.
#define ISSUE(s, buf) do {                                              \
        const ushort* gp_ = yb + (size_t)(s) * SRW * C_;                \
        gload16(gp_,           (void*)&stg[wid][buf][0]);               \
        gload16(gp_ + 64 * 8,  (void*)&stg[wid][buf][64]);              \
    } while (0)

// ---------------------------------------------------------------------------
// PASS 1: min d^2 over this block's y-half -> global atomicMin of d bits.
__global__ __launch_bounds__(1024, 8) void pass1_kernel(const ushort* __restrict__ xn,
                                                        const ushort* __restrict__ yn,
                                                        unsigned* __restrict__ dmin_u) {
    __shared__ short8 stg[NW][2][SRW * 8];         // 64 KB
    __shared__ float  red[NW][XR];                 // 4 KB
    PASS_SETUP

    float m2[4] = {INFINITY, INFINITY, INFINITY, INFINITY};
    ISSUE(0, 0);
    for (int s = 0; s < NSW; ++s) {
        int cur = s & 1;
        if (s + 1 < NSW) { ISSUE(s + 1, cur ^ 1); WAIT_VMCNT(2); }
        else             { WAIT_VMCNT(0); }
        __builtin_amdgcn_sched_barrier(0);
        int p = lrow, q = p & 7;
        short8 ya0 = stg[wid][cur][p * 8 + (kgrp ^ q)];         // k 0..31
        short8 ya1 = stg[wid][cur][p * 8 + ((kgrp + 4) ^ q)];   // k 32..63
#pragma unroll
        for (int xt = 0; xt < 4; ++xt) {
            floatx4 acc = {2.0f, 2.0f, 2.0f, 2.0f};
            acc = __builtin_amdgcn_mfma_f32_16x16x32_bf16(ya0, xf0[xt], acc, 0, 0, 0);
            acc = __builtin_amdgcn_mfma_f32_16x16x32_bf16(ya1, xf1[xt], acc, 0, 0, 0);
            m2[xt] = fminf(fminf(fminf(acc[0], acc[1]), acc[2]),
                           fminf(acc[3], m2[xt]));
        }
    }

    // Combine the 4 k-groups, then the 16 waves (disjoint y-subsets).
#pragma unroll
    for (int off = 16; off < 64; off <<= 1)
#pragma unroll
        for (int xt = 0; xt < 4; ++xt)
            m2[xt] = fminf(m2[xt], __shfl_xor(m2[xt], off));
    if (kgrp == 0)
#pragma unroll
        for (int xt = 0; xt < 4; ++xt) red[wid][xt * 16 + lrow] = m2[xt];
    __syncthreads();
    if (tid < XR) {
        float m = red[0][tid];
#pragma unroll
        for (int w = 1; w < NW; ++w) m = fminf(m, red[w][tid]);
        float d = sqrtf(fmaxf(m, 0.0f));
        atomicMin(&dmin_u[b * HW + nbase + tid], __float_as_uint(d));
    }
}

// ---------------------------------------------------------------------------
// PASS 2: S_row = sum exp2((dmin-d)*kk2) over this block's y-half; one
// atomicAdd of sum(1/S+eps) pairs... S partials combine via atomicAdd on S?
// No: each row's S is split across the 2 half-blocks -> accumulate partial
// exp-sums into global Sacc with atomicAdd, then LAST block (cnt) reduces
// 1/S.  To keep one pass: Sacc[row] += partial; last block of all 512
// computes sum(1/Sacc+eps) over 16384 rows and writes out.
__global__ __launch_bounds__(1024, 8) void pass2_kernel(const ushort* __restrict__ xn,
                                                        const ushort* __restrict__ yn,
                                                        const unsigned* __restrict__ dmin_u,
                                                        float* __restrict__ Sacc,
                                                        unsigned* __restrict__ cnt,
                                                        float* __restrict__ out) {
    __shared__ short8 stg[NW][2][SRW * 8];         // 64 KB
    __shared__ float  red[NW][XR];                 // 4 KB
    PASS_SETUP

    float kk2[4], c02[4];
#pragma unroll
    for (int xt = 0; xt < 4; ++xt) {
        float dm = __uint_as_float(dmin_u[b * HW + nbase + xt * 16 + lrow]);
        kk2[xt] = LOG2E / (SIGMA * (dm + EPS_MIN));
        c02[xt] = dm * kk2[xt];
    }

    float s2[4] = {0.0f, 0.0f, 0.0f, 0.0f};
    ISSUE(0, 0);
    for (int s = 0; s < NSW; ++s) {
        int cur = s & 1;
        if (s + 1 < NSW) { ISSUE(s + 1, cur ^ 1); WAIT_VMCNT(2); }
        else             { WAIT_VMCNT(0); }
        __builtin_amdgcn_sched_barrier(0);
        int p = lrow, q = p & 7;
        short8 ya0 = stg[wid][cur][p * 8 + (kgrp ^ q)];
        short8 ya1 = stg[wid][cur][p * 8 + ((kgrp + 4) ^ q)];
#pragma unroll
        for (int xt = 0; xt < 4; ++xt) {
            floatx4 acc = {2.0f, 2.0f, 2.0f, 2.0f};
            acc = __builtin_amdgcn_mfma_f32_16x16x32_bf16(ya0, xf0[xt], acc, 0, 0, 0);
            acc = __builtin_amdgcn_mfma_f32_16x16x32_bf16(ya1, xf1[xt], acc, 0, 0, 0);
            float d0 = __builtin_amdgcn_sqrtf(acc[0]);   // d^2 >= ~1.1
            float d1 = __builtin_amdgcn_sqrtf(acc[1]);
            float d2 = __builtin_amdgcn_sqrtf(acc[2]);
            float d3 = __builtin_amdgcn_sqrtf(acc[3]);
            s2[xt] += __builtin_amdgcn_exp2f(fmaf(-kk2[xt], d0, c02[xt]));
            s2[xt] += __builtin_amdgcn_exp2f(fmaf(-kk2[xt], d1, c02[xt]));
            s2[xt] += __builtin_amdgcn_exp2f(fmaf(-kk2[xt], d2, c02[xt]));
            s2[xt] += __builtin_amdgcn_exp2f(fmaf(-kk2[xt], d3, c02[xt]));
        }
    }

#pragma unroll
    for (int off = 16; off < 64; off <<= 1)
#pragma unroll
        for (int xt = 0; xt < 4; ++xt)
            s2[xt] += __shfl_xor(s2[xt], off);
    if (kgrp == 0)
#pragma unroll
        for (int xt = 0; xt < 4; ++xt) red[wid][xt * 16 + lrow] = s2[xt];
    __syncthreads();

    // Partial S for this y-half -> global accumulate.
    if (tid < XR) {
        float Ssum = red[0][tid];
#pragma unroll
        for (int w = 1; w < NW; ++w) Ssum += red[w][tid];
        atomicAdd(&Sacc[b * HW + nbase + tid], Ssum);
    }
    __syncthreads();

    // Last block of the whole grid computes the final scalar.
    if (tid == 0) {
        __threadfence();
        if (atomicAdd(cnt, 1u) == GRID - 1) *cnt = 0xFFFFFFFFu;  // elect
    }
    __syncthreads();
    __threadfence();
    if (*((volatile unsigned*)cnt) == 0xFFFFFFFFu) {
        // This block is last: all Sacc complete.  1024 threads reduce 16384.
        __shared__ float fin[NW];
        float acc = 0.0f;
        for (int i = tid; i < ROWS; i += 1024)
            acc += __builtin_amdgcn_rcpf(Sacc[i]) + EPS_MIN;
#pragma unroll
        for (int off = 32; off > 0; off >>= 1) acc += __shfl_down(acc, off);
        if (lane == 0) fin[wid] = acc;
        __syncthreads();
        if (tid == 0) {
            float t = 0.0f;
#pragma unroll
            for (int w = 0; w < NW; ++w) t += fin[w];
            out[0] = -logf(t / (float)ROWS);
        }
    }
}
#undef ISSUE
#undef PASS_SETUP

// ---------------------------------------------------------------------------
// Zero Sacc (16384 floats) -- folded into a tiny kernel with big grid-stride.
__global__ __launch_bounds__(256) void zs_kernel(float* __restrict__ Sacc) {
    int i = blockIdx.x * 256 + threadIdx.x;
    if (i < ROWS) Sacc[i] = 0.0f;
}

// ---------------------------------------------------------------------------
extern "C" void kernel_launch(void* const* d_in, const int* in_sizes, int n_in,
                              void* d_out, int out_size, void* d_ws, size_t ws_size,
                              hipStream_t stream) {
    const float* x = (const float*)d_in[0];
    const float* y = (const float*)d_in[1];
    float* out = (float*)d_out;

    char* ws = (char*)d_ws;
    size_t nrm_bytes = (size_t)ROWS * C_ * sizeof(ushort);   // 2 MB each
    ushort*   xn    = (ushort*)(ws);
    ushort*   yn    = (ushort*)(ws + nrm_bytes);
    unsigned* dmin_u = (unsigned*)(ws + 2 * nrm_bytes);
    float*    Sacc   = (float*)(ws + 2 * nrm_bytes + ROWS * sizeof(unsigned));
    float*    total  = (float*)(ws + 2 * nrm_bytes + ROWS * 8);
    unsigned* cnt    = (unsigned*)(ws + 2 * nrm_bytes + ROWS * 8 + 16);

    hipLaunchKernelGGL(zs_kernel, dim3(ROWS / 256), dim3(256), 0, stream, Sacc);
    hipLaunchKernelGGL(nrm_kernel, dim3(4 * ROWS / 256), dim3(256), 0, stream,
                       x, y, xn, yn, dmin_u, total, cnt);
    hipLaunchKernelGGL(pass1_kernel, dim3(GRID), dim3(1024), 0, stream,
                       xn, yn, dmin_u);
    hipLaunchKernelGGL(pass2_kernel, dim3(GRID), dim3(1024), 0, stream,
                       xn, yn, dmin_u, Sacc, cnt, out);
}